// Round 4
// baseline (3225.174 us; speedup 1.0000x reference)
//
#include <hip/hip_runtime.h>
#include <stdint.h>

#define B_     4096
#define IN_DIM 2048
#define KCB    8192
#define DD     256
#define SS     8
#define ND     (SS*DD)   // 2048

// ---------------------------------------------------------------------------
// SGEMM (NT): C[M,N] = A[M,K] * B[N,K]^T + bias[N].  Row-major everything.
// BM=BN=128, BK=16, 256 threads, 8x8 micro-tile.
// ---------------------------------------------------------------------------
#define BM 128
#define BN 128
#define BK 16
#define LDSP 132   // padded leading dim: 16B align kept, bank conflicts broken

__global__ __launch_bounds__(256) void sgemm_nt_bias_v4(
    const float* __restrict__ A, const float* __restrict__ Bm,
    const float* __restrict__ bias, float* __restrict__ C,
    int M, int N, int K)
{
    __shared__ float As[BK][LDSP];
    __shared__ float Bs[BK][LDSP];
    const int tid = threadIdx.x;
    const int tx  = tid & 15;       // n
    const int ty  = tid >> 4;       // m
    const int m0  = blockIdx.y * BM;
    const int n0  = blockIdx.x * BN;

    float acc[8][8];
    #pragma unroll
    for (int i = 0; i < 8; ++i)
        #pragma unroll
        for (int j = 0; j < 8; ++j) acc[i][j] = 0.f;

    for (int kt = 0; kt < K; kt += BK) {
        #pragma unroll
        for (int l = 0; l < 2; ++l) {
            int idx = tid + l * 256;          // 0..511
            int row = idx >> 2;               // 0..127
            int c4  = (idx & 3) * 4;          // 0,4,8,12
            float4 av = *(const float4*)(A  + (size_t)(m0 + row) * K + kt + c4);
            As[c4+0][row] = av.x; As[c4+1][row] = av.y;
            As[c4+2][row] = av.z; As[c4+3][row] = av.w;
            float4 bv = *(const float4*)(Bm + (size_t)(n0 + row) * K + kt + c4);
            Bs[c4+0][row] = bv.x; Bs[c4+1][row] = bv.y;
            Bs[c4+2][row] = bv.z; Bs[c4+3][row] = bv.w;
        }
        __syncthreads();
        #pragma unroll
        for (int kk = 0; kk < BK; ++kk) {
            float a[8], b[8];
            *(float4*)&a[0] = *(const float4*)&As[kk][ty*8];
            *(float4*)&a[4] = *(const float4*)&As[kk][ty*8+4];
            *(float4*)&b[0] = *(const float4*)&Bs[kk][tx*8];
            *(float4*)&b[4] = *(const float4*)&Bs[kk][tx*8+4];
            #pragma unroll
            for (int i = 0; i < 8; ++i)
                #pragma unroll
                for (int j = 0; j < 8; ++j) acc[i][j] += a[i] * b[j];
        }
        __syncthreads();
    }

    #pragma unroll
    for (int i = 0; i < 8; ++i) {
        int m = m0 + ty*8 + i;
        #pragma unroll
        for (int j = 0; j < 8; j += 4) {
            int n = n0 + tx*8 + j;
            float4 v;
            v.x = acc[i][j+0] + bias[n+0];
            v.y = acc[i][j+1] + bias[n+1];
            v.z = acc[i][j+2] + bias[n+2];
            v.w = acc[i][j+3] + bias[n+3];
            *(float4*)(C + (size_t)m * N + n) = v;
        }
    }
}

// ---------------------------------------------------------------------------
// z_sq[b*S+s] = fp32 sum_d z[b, s*256+d]^2.  One wave per (b,s) row.
// (Shuffle-tree reduction ~ pairwise order: matches np's pairwise z_sq to a
//  few ULP; Z cancels in the distance ordering so few-ULP error is benign.)
// ---------------------------------------------------------------------------
__global__ __launch_bounds__(256) void zsq_v4(
    const float* __restrict__ Z, float* __restrict__ zsq)
{
    int gw   = (blockIdx.x * 256 + threadIdx.x) >> 6;   // row = b*8+s
    int lane = threadIdx.x & 63;
    float4 v = *(const float4*)(Z + (size_t)gw * DD + lane * 4);
    float ssum = v.x*v.x + v.y*v.y + v.z*v.z + v.w*v.w;
    #pragma unroll
    for (int off = 32; off; off >>= 1) ssum += __shfl_down(ssum, off, 64);
    if (lane == 0) zsq[gw] = ssum;
}

// ---------------------------------------------------------------------------
// Distance + argmin, REPRODUCING the reference's fp32 quantization:
//   d[b,s,k] = fp32( z_sq[b,s] - 2*cross )      (e_sq < ULP(z_sq)/2 -> absorbed)
// The +z_sq(~256) offset collapses near-ties to identical fp32 values, exactly
// as in the np reference; packed u64 = (mono_bits(d)<<32)|k then u64-min gives
// the lowest-k tie-break matching jnp.argmin.
// grid = (K/1024, B/128, S), block 256. Race-free: per-block min to unique slot.
// ---------------------------------------------------------------------------
__global__ __launch_bounds__(256) void dist_argmin_v4(
    const float* __restrict__ Z,    // [B, 2048]
    const float* __restrict__ CB,   // [S, K, D]
    const float* __restrict__ zsq,  // [B*S]
    unsigned long long* __restrict__ minp)  // [B*S][8]
{
    __shared__ float As[BK][LDSP];
    __shared__ float Bs[BK][LDSP];
    const int tid = threadIdx.x;
    const int tx  = tid & 15;
    const int ty  = tid >> 4;
    const int s     = blockIdx.z;
    const int m0    = blockIdx.y * 128;
    const int nbase = blockIdx.x * 1024;
    const float* Az = Z  + (size_t)s * DD;        // lda = ND
    const float* Bc = CB + (size_t)s * KCB * DD;  // row stride = DD

    float Zr[8];
    #pragma unroll
    for (int i = 0; i < 8; ++i) Zr[i] = zsq[(size_t)(m0 + ty*8 + i) * SS + s];

    unsigned long long lmin[8];
    #pragma unroll
    for (int i = 0; i < 8; ++i) lmin[i] = ~0ull;

    for (int nt = 0; nt < 8; ++nt) {
        const int n0 = nbase + nt * 128;
        float acc[8][8];
        #pragma unroll
        for (int i = 0; i < 8; ++i)
            #pragma unroll
            for (int j = 0; j < 8; ++j) acc[i][j] = 0.f;

        for (int kt = 0; kt < DD; kt += BK) {
            #pragma unroll
            for (int l = 0; l < 2; ++l) {
                int idx = tid + l * 256;
                int row = idx >> 2;
                int c4  = (idx & 3) * 4;
                float4 av = *(const float4*)(Az + (size_t)(m0 + row) * ND + kt + c4);
                As[c4+0][row] = av.x; As[c4+1][row] = av.y;
                As[c4+2][row] = av.z; As[c4+3][row] = av.w;
                float4 bv = *(const float4*)(Bc + (size_t)(n0 + row) * DD + kt + c4);
                Bs[c4+0][row] = bv.x; Bs[c4+1][row] = bv.y;
                Bs[c4+2][row] = bv.z; Bs[c4+3][row] = bv.w;
            }
            __syncthreads();
            #pragma unroll
            for (int kk = 0; kk < BK; ++kk) {
                float a[8], b[8];
                *(float4*)&a[0] = *(const float4*)&As[kk][ty*8];
                *(float4*)&a[4] = *(const float4*)&As[kk][ty*8+4];
                *(float4*)&b[0] = *(const float4*)&Bs[kk][tx*8];
                *(float4*)&b[4] = *(const float4*)&Bs[kk][tx*8+4];
                #pragma unroll
                for (int i = 0; i < 8; ++i)
                    #pragma unroll
                    for (int j = 0; j < 8; ++j) acc[i][j] += a[i] * b[j];
            }
            __syncthreads();
        }

        // epilogue: quantized score (fp32 round-half-even in HW, same as np),
        // pack, running min
        #pragma unroll
        for (int i = 0; i < 8; ++i) {
            #pragma unroll
            for (int j = 0; j < 8; ++j) {
                int n = n0 + tx*8 + j;
                float sc = Zr[i] - 2.f * acc[i][j];   // fp32: ties collapse here
                unsigned u = __float_as_uint(sc);
                u = (sc < 0.f) ? ~u : (u | 0x80000000u);
                unsigned long long p = ((unsigned long long)u << 32) | (unsigned)n;
                if (p < lmin[i]) lmin[i] = p;
            }
        }
    }

    // min across the 16 tx lanes (same ty = same rows, same wave)
    #pragma unroll
    for (int i = 0; i < 8; ++i) {
        unsigned long long v = lmin[i];
        #pragma unroll
        for (int off = 1; off < 16; off <<= 1) {
            unsigned long long o = __shfl_xor(v, off, 64);
            if (o < v) v = o;
        }
        lmin[i] = v;
    }
    if (tx == 0) {
        #pragma unroll
        for (int i = 0; i < 8; ++i) {
            int m = m0 + ty*8 + i;
            minp[((size_t)m * SS + s) * 8 + blockIdx.x] = lmin[i];
        }
    }
}

// ---------------------------------------------------------------------------
// Merge the 8 per-block minima per row -> final code.
// ---------------------------------------------------------------------------
__global__ __launch_bounds__(256) void reduce_min_v4(
    const unsigned long long* __restrict__ minp,   // [B*S][8]
    int* __restrict__ kfinal)
{
    int row = blockIdx.x * 256 + threadIdx.x;
    if (row >= B_ * SS) return;
    unsigned long long b1 = ~0ull;
    #pragma unroll
    for (int j = 0; j < 8; ++j) {
        unsigned long long v = minp[(size_t)row * 8 + j];
        if (v < b1) b1 = v;
    }
    kfinal[row] = (int)(b1 & 0xFFFFFFFFull);
}

// ---------------------------------------------------------------------------
// Gather quantized vectors, emit codes (as float), histogram counts.
// ---------------------------------------------------------------------------
__global__ __launch_bounds__(256) void gather_v4(
    const float* __restrict__ CB,
    const int* __restrict__ kfinal,
    float* __restrict__ quant,   // [B, 2048]
    float* __restrict__ codes,   // [B, S]
    unsigned* __restrict__ counts) // [S, K]
{
    const int b = blockIdx.x;
    const int tid = threadIdx.x;
    __shared__ int ks[SS];
    if (tid < SS) {
        int k = kfinal[(size_t)b * SS + tid];
        ks[tid] = k;
        codes[(size_t)b * SS + tid] = (float)k;
        atomicAdd(&counts[(size_t)tid * KCB + k], 1u);
    }
    __syncthreads();
    #pragma unroll
    for (int l = 0; l < 2; ++l) {
        int f  = tid + l * 256;
        int s  = f >> 6;
        int d4 = f & 63;
        float4 v = *(const float4*)(CB + ((size_t)s * KCB + ks[s]) * DD + d4 * 4);
        *(float4*)(quant + (size_t)b * ND + s * DD + d4 * 4) = v;
    }
}

// ---------------------------------------------------------------------------
__global__ __launch_bounds__(256) void perp_v4(
    const unsigned* __restrict__ counts, float* __restrict__ out)
{
    __shared__ float red[256];
    const int tid = threadIdx.x;
    const float inv = 1.0f / (float)B_;
    float sumP = 0.f;
    for (int s = 0; s < SS; ++s) {
        float h = 0.f;
        for (int k = tid; k < KCB; k += 256) {
            float p = (float)counts[(size_t)s * KCB + k] * inv;
            h += p * logf(p + 1e-10f);
        }
        red[tid] = h;
        __syncthreads();
        for (int w = 128; w; w >>= 1) {
            if (tid < w) red[tid] += red[tid + w];
            __syncthreads();
        }
        if (tid == 0) sumP += expf(-red[0]);
        __syncthreads();
    }
    if (tid == 0) out[0] = sumP / (float)SS;
}

// ---------------------------------------------------------------------------
extern "C" void kernel_launch(void* const* d_in, const int* in_sizes, int n_in,
                              void* d_out, int out_size, void* d_ws, size_t ws_size,
                              hipStream_t stream)
{
    const float* x     = (const float*)d_in[0];
    const float* enc_w = (const float*)d_in[1];
    const float* enc_b = (const float*)d_in[2];
    const float* cb    = (const float*)d_in[3];
    const float* dec_w = (const float*)d_in[4];
    const float* dec_b = (const float*)d_in[5];

    float* out0 = (float*)d_out;                       // x_recon (holds z temporarily)
    float* out1 = out0 + (size_t)B_ * ND;              // quantized_flat
    float* out2 = out1 + (size_t)B_ * ND;              // codes (as float)
    float* out3 = out2 + (size_t)B_ * SS;              // avg_perplexity scalar

    // workspace layout:
    //   minp   [B*S][8] u64 : 2 MB   (fully overwritten each call)
    //   counts [S*K] u32    : 256 KB (memset 0)
    //   kfinal [B*S] i32    : 128 KB
    //   zsq    [B*S] f32    : 128 KB
    char* wsb = (char*)d_ws;
    unsigned long long* minp = (unsigned long long*)wsb;
    size_t off = (size_t)B_ * SS * 8 * sizeof(unsigned long long);
    unsigned* counts = (unsigned*)(wsb + off);  off += (size_t)SS * KCB * 4;
    int*      kfinal = (int*)(wsb + off);       off += (size_t)B_ * SS * 4;
    float*    zsq    = (float*)(wsb + off);

    hipMemsetAsync(counts, 0, (size_t)SS * KCB * 4, stream);

    // 1. encoder GEMM: z -> out0 (temp)
    dim3 g1(ND / BN, B_ / BM);   // (16, 32)
    sgemm_nt_bias_v4<<<g1, 256, 0, stream>>>(x, enc_w, enc_b, out0, B_, ND, IN_DIM);

    // 2. per-(b,s) z_sq (the constant that drives the fp32 quantization)
    zsq_v4<<<(B_ * SS) / 4, 256, 0, stream>>>(out0, zsq);

    // 3. fused distance + argmin with reference-matching fp32 rounding
    dim3 g2(KCB / 1024, B_ / 128, SS);   // (8, 32, 8)
    dist_argmin_v4<<<g2, 256, 0, stream>>>(out0, cb, zsq, minp);

    // 4. merge per-block minima -> codes
    reduce_min_v4<<<(B_ * SS + 255) / 256, 256, 0, stream>>>(minp, kfinal);

    // 5. gather + codes + histogram
    gather_v4<<<B_, 256, 0, stream>>>(cb, kfinal, out1, out2, counts);

    // 6. decoder GEMM: x_recon -> out0 (overwrites z)
    sgemm_nt_bias_v4<<<g1, 256, 0, stream>>>(out1, dec_w, dec_b, out0, B_, IN_DIM, ND);

    // 7. perplexity scalar
    perp_v4<<<1, 256, 0, stream>>>(counts, out3);
}